// Round 3
// baseline (4875.380 us; speedup 1.0000x reference)
//
#include <hip/hip_runtime.h>
#include <cstddef>

// B=64, T=512, H=256. Float inputs fp32 (runtime-detected, bf16 fallback).
// Output fp32: [out_s (B*T), out_e (B*T)].
// ws layout (bytes):
//   0        WK2   5*65536 f32  (W1f, W1fq+W1fm, W1afq+W1afm, Wr, Wh)
//   1310720  Urp   128*256 u32  (bf16 pairs along i)
//   1441792  Uhp   128*256 u32
//   1572864  qw1   64*256 f32   (b1 + q@(W1m+W1q))
//   1638400  qs    64 f32       (bs + q@Ws[0:256])
//   1638656  qe    64 f32
//   1638912  att   64*512 f32
//   1769984  g     64*512 f32
//   1901056  xrh   64*512*256 u32  (bf16(xr+br) | bf16(xh+bh)<<16)
//   35455488 ep    64*512*256 bf16 (e_outputs)
//   52232704 mode  int (0 = inputs are bf16, 1 = inputs are fp32)

static __device__ __forceinline__ float b2f(unsigned short u) {
  return __uint_as_float(((unsigned)u) << 16);
}
static __device__ __forceinline__ float blo(unsigned w) { return __uint_as_float(w << 16); }
static __device__ __forceinline__ float bhi(unsigned w) { return __uint_as_float(w & 0xffff0000u); }
static __device__ __forceinline__ unsigned short f2b(float f) {
  unsigned u = __float_as_uint(f);
  u += 0x7fffu + ((u >> 16) & 1u);  // RNE
  return (unsigned short)(u >> 16);
}
// adaptive input loads (md: 0=bf16 data, 1=fp32 data)
static __device__ __forceinline__ float ldf(const void* b, size_t i, int md) {
  return md ? ((const float*)b)[i] : b2f(((const unsigned short*)b)[i]);
}
static __device__ __forceinline__ unsigned short ldb(const void* b, size_t i, int md) {
  return md ? f2b(((const float*)b)[i]) : ((const unsigned short*)b)[i];
}

// ---------------- dtype detection ----------------
__global__ void k_detect(const void* __restrict__ fact, int* __restrict__ mode) {
  int tid = threadIdx.x;  // 256
  const unsigned short* u = (const unsigned short*)fact;
  float v = fabsf(b2f(u[2 * tid]));  // if fp32 data: low mantissa bits -> huge/NaN
  if (!(v == v)) v = 1e30f;
  for (int o = 32; o > 0; o >>= 1) v = fmaxf(v, __shfl_xor(v, o));
  __shared__ float red[4];
  int wave = tid >> 6, lane = tid & 63;
  if (lane == 0) red[wave] = v;
  __syncthreads();
  if (tid == 0) {
    float m = fmaxf(fmaxf(red[0], red[1]), fmaxf(red[2], red[3]));
    mode[0] = (m > 1e4f) ? 1 : 0;
  }
}

// ---------------- prep: combined weights + packed Ur/Uh ----------------
__global__ void k_prep_w(const void* __restrict__ W1,
                         const void* __restrict__ Wr,
                         const void* __restrict__ Wh,
                         const void* __restrict__ Ur,
                         const void* __restrict__ Uh,
                         const int* __restrict__ mode,
                         float* __restrict__ WK2,
                         unsigned* __restrict__ Urp,
                         unsigned* __restrict__ Uhp) {
  int md = *mode;
  int idx = blockIdx.x * 256 + threadIdx.x;  // 0..65535
  int i = idx >> 8, j = idx & 255;
  WK2[0 * 65536 + idx] = ldf(W1, idx, md);  // rows [0,256): f
  WK2[1 * 65536 + idx] = ldf(W1, (size_t)(768 + i) * 256 + j, md) + ldf(W1, (size_t)(1024 + i) * 256 + j, md);   // f*q
  WK2[2 * 65536 + idx] = ldf(W1, (size_t)(1280 + i) * 256 + j, md) + ldf(W1, (size_t)(1536 + i) * 256 + j, md);  // |f-q|
  WK2[3 * 65536 + idx] = ldf(Wr, idx, md);
  WK2[4 * 65536 + idx] = ldf(Wh, idx, md);
  if (i < 128) {
    Urp[idx] = (unsigned)ldb(Ur, (size_t)(2 * i) * 256 + j, md) |
               ((unsigned)ldb(Ur, (size_t)(2 * i + 1) * 256 + j, md) << 16);
    Uhp[idx] = (unsigned)ldb(Uh, (size_t)(2 * i) * 256 + j, md) |
               ((unsigned)ldb(Uh, (size_t)(2 * i + 1) * 256 + j, md) << 16);
  }
}

// ---------------- prep: q-dependent vectors ----------------
__global__ void k_prep_q(const void* __restrict__ q,
                         const void* __restrict__ W1,
                         const void* __restrict__ b1,
                         const void* __restrict__ Ws,
                         const void* __restrict__ bs,
                         const void* __restrict__ We,
                         const void* __restrict__ be,
                         const int* __restrict__ mode,
                         float* __restrict__ qw1,
                         float* __restrict__ qs,
                         float* __restrict__ qe) {
  __shared__ float qsh[256];
  __shared__ float reds[4], rede[4];
  int md = *mode;
  int b = blockIdx.x, tid = threadIdx.x;
  float qv = ldf(q, (size_t)b * 256 + tid, md);
  qsh[tid] = qv;
  __syncthreads();
  float acc = ldf(b1, tid, md);
  for (int i = 0; i < 256; ++i) {
    float w = ldf(W1, (size_t)(256 + i) * 256 + tid, md) + ldf(W1, (size_t)(512 + i) * 256 + tid, md);
    acc = fmaf(qsh[i], w, acc);
  }
  qw1[b * 256 + tid] = acc;
  float ps = qv * ldf(Ws, tid, md);
  float pe = qv * ldf(We, tid, md);
  for (int o = 32; o > 0; o >>= 1) { ps += __shfl_down(ps, o); pe += __shfl_down(pe, o); }
  int wave = tid >> 6, lane = tid & 63;
  if (lane == 0) { reds[wave] = ps; rede[wave] = pe; }
  __syncthreads();
  if (tid == 0) {
    qs[b] = ldf(bs, 0, md) + reds[0] + reds[1] + reds[2] + reds[3];
    qe[b] = ldf(be, 0, md) + rede[0] + rede[1] + rede[2] + rede[3];
  }
}

// ---------------- main GEMM: att pre-softmax + xr/xh ----------------
__launch_bounds__(256, 2)
__global__ void k_main(const void* __restrict__ fact,
                       const void* __restrict__ q,
                       const float* __restrict__ WK2,
                       const float* __restrict__ qw1,
                       const void* __restrict__ W2,
                       const void* __restrict__ b2v,
                       const void* __restrict__ br,
                       const void* __restrict__ bh,
                       const int* __restrict__ mode,
                       float* __restrict__ att,
                       unsigned* __restrict__ xrh) {
  __shared__ __align__(16) float sfT[256 * 20];  // [feature i][row r], stride 20
  __shared__ __align__(16) float sqT[256 * 20];
  __shared__ __align__(16) float saT[256 * 20];
  __shared__ float wsc[4 * 16];
  int md = *mode;
  int blk = blockIdx.x;
  int b = blk >> 5, t0 = (blk & 31) * 16;
  int tid = threadIdx.x;
  float qv = ldf(q, (size_t)b * 256 + tid, md);
  for (int r = 0; r < 16; ++r) {
    float f = ldf(fact, ((size_t)(b * 512 + t0 + r)) * 256 + tid, md);
    sfT[tid * 20 + r] = f;
    sqT[tid * 20 + r] = f * qv;
    saT[tid * 20 + r] = fabsf(f - qv);
  }
  __syncthreads();
  int jq = tid >> 2, rq = tid & 3;
  float u[4][4] = {{0}}, ar[4][4] = {{0}}, ah[4][4] = {{0}};
  const float* w0 = WK2 + jq * 4;
  const float* w1 = w0 + 65536;
  const float* w2 = w0 + 2 * 65536;
  const float* w3 = w0 + 3 * 65536;
  const float* w4 = w0 + 4 * 65536;
  for (int i = 0; i < 256; ++i) {
    float4 wf = *(const float4*)(w0 + i * 256);
    float4 wq = *(const float4*)(w1 + i * 256);
    float4 wa = *(const float4*)(w2 + i * 256);
    float4 wr4 = *(const float4*)(w3 + i * 256);
    float4 wh4 = *(const float4*)(w4 + i * 256);
    float4 s1 = *(const float4*)(sfT + i * 20 + rq * 4);
    float4 s2 = *(const float4*)(sqT + i * 20 + rq * 4);
    float4 s3 = *(const float4*)(saT + i * 20 + rq * 4);
    float s1a[4] = {s1.x, s1.y, s1.z, s1.w};
    float s2a[4] = {s2.x, s2.y, s2.z, s2.w};
    float s3a[4] = {s3.x, s3.y, s3.z, s3.w};
    float wfa[4] = {wf.x, wf.y, wf.z, wf.w};
    float wqa[4] = {wq.x, wq.y, wq.z, wq.w};
    float waa[4] = {wa.x, wa.y, wa.z, wa.w};
    float wra[4] = {wr4.x, wr4.y, wr4.z, wr4.w};
    float wha[4] = {wh4.x, wh4.y, wh4.z, wh4.w};
#pragma unroll
    for (int rr = 0; rr < 4; ++rr) {
#pragma unroll
      for (int jj = 0; jj < 4; ++jj) {
        u[rr][jj] = fmaf(s1a[rr], wfa[jj], u[rr][jj]);
        u[rr][jj] = fmaf(s2a[rr], wqa[jj], u[rr][jj]);
        u[rr][jj] = fmaf(s3a[rr], waa[jj], u[rr][jj]);
        ar[rr][jj] = fmaf(s1a[rr], wra[jj], ar[rr][jj]);
        ah[rr][jj] = fmaf(s1a[rr], wha[jj], ah[rr][jj]);
      }
    }
  }
  float qwv[4], w2v[4], brv[4], bhv[4];
#pragma unroll
  for (int jj = 0; jj < 4; ++jj) {
    int j = jq * 4 + jj;
    qwv[jj] = qw1[b * 256 + j];
    w2v[jj] = ldf(W2, j, md);
    brv[jj] = ldf(br, j, md);
    bhv[jj] = ldf(bh, j, md);
  }
  float patt[4];
#pragma unroll
  for (int rr = 0; rr < 4; ++rr) {
    float p = 0.f;
#pragma unroll
    for (int jj = 0; jj < 4; ++jj) {
      float hid = tanhf(u[rr][jj] + qwv[jj]);
      p = fmaf(hid, w2v[jj], p);
    }
    p += __shfl_down(p, 4);
    p += __shfl_down(p, 8);
    p += __shfl_down(p, 16);
    p += __shfl_down(p, 32);
    patt[rr] = p;
  }
  int wave = tid >> 6, lane = tid & 63;
  if (lane < 4) {
#pragma unroll
    for (int rr = 0; rr < 4; ++rr) wsc[wave * 16 + lane * 4 + rr] = patt[rr];
  }
  __syncthreads();
  if (tid < 16) {
    float s = wsc[tid] + wsc[16 + tid] + wsc[32 + tid] + wsc[48 + tid];
    att[b * 512 + t0 + tid] = s + ldf(b2v, 0, md);
  }
#pragma unroll
  for (int rr = 0; rr < 4; ++rr) {
    int t = t0 + rq * 4 + rr;
    unsigned vv[4];
#pragma unroll
    for (int jj = 0; jj < 4; ++jj) {
      unsigned lo = f2b(ar[rr][jj] + brv[jj]);
      unsigned hi = f2b(ah[rr][jj] + bhv[jj]);
      vv[jj] = lo | (hi << 16);
    }
    uint4 v;
    v.x = vv[0]; v.y = vv[1]; v.z = vv[2]; v.w = vv[3];
    *(uint4*)(xrh + ((size_t)(b * 512 + t)) * 256 + jq * 4) = v;
  }
}

// ---------------- softmax over T per batch ----------------
__global__ void k_softmax(const float* __restrict__ att, float* __restrict__ g) {
  __shared__ float red[8];
  int b = blockIdx.x, tid = threadIdx.x;  // 512 threads
  float v = att[b * 512 + tid];
  float m = v;
  for (int o = 32; o > 0; o >>= 1) m = fmaxf(m, __shfl_xor(m, o));
  int wave = tid >> 6, lane = tid & 63;
  if (lane == 0) red[wave] = m;
  __syncthreads();
  m = red[0];
#pragma unroll
  for (int w = 1; w < 8; ++w) m = fmaxf(m, red[w]);
  float e = __expf(v - m);
  float s = e;
  for (int o = 32; o > 0; o >>= 1) s += __shfl_xor(s, o);
  __syncthreads();
  if (lane == 0) red[wave] = s;
  __syncthreads();
  s = red[0] + red[1] + red[2] + red[3] + red[4] + red[5] + red[6] + red[7];
  g[b * 512 + tid] = e / s;
}

// ---------------- sequential GRU scan: one block per batch ----------------
__launch_bounds__(256, 1)
__global__ void k_scan(const unsigned* __restrict__ Urp,
                       const unsigned* __restrict__ Uhp,
                       const unsigned* __restrict__ xrh,
                       const float* __restrict__ g,
                       const int* __restrict__ input_len,
                       unsigned short* __restrict__ ep) {
  __shared__ __align__(16) float hsh[256];
  __shared__ __align__(16) float rhsh[256];
  __shared__ float gsh[512];
  int b = blockIdx.x, tid = threadIdx.x;
  unsigned wr[128], wh[128];
#pragma unroll
  for (int p = 0; p < 128; ++p) wr[p] = Urp[p * 256 + tid];
#pragma unroll
  for (int p = 0; p < 128; ++p) wh[p] = Uhp[p * 256 + tid];
  gsh[tid] = g[b * 512 + tid];
  gsh[256 + tid] = g[b * 512 + 256 + tid];
  hsh[tid] = 0.f;
  int len = input_len[b];
  float hj = 0.f;
  const unsigned* xp = xrh + (size_t)b * 512 * 256 + tid;
  unsigned nxt = xp[0];
  __syncthreads();
  for (int t = 0; t < 512; ++t) {
    unsigned cur = nxt;
    nxt = xp[(size_t)((t + 1) & 511) * 256];
    float gt = gsh[t];
    float a0 = 0, a1 = 0, a2 = 0, a3 = 0;
    const float4* h4 = (const float4*)hsh;
#pragma unroll
    for (int qi = 0; qi < 64; ++qi) {
      float4 hv = h4[qi];
      unsigned p0 = wr[2 * qi], p1 = wr[2 * qi + 1];
      a0 = fmaf(blo(p0), hv.x, a0);
      a1 = fmaf(bhi(p0), hv.y, a1);
      a2 = fmaf(blo(p1), hv.z, a2);
      a3 = fmaf(bhi(p1), hv.w, a3);
    }
    float xr_t = b2f((unsigned short)(cur & 0xffffu));
    float xh_t = b2f((unsigned short)(cur >> 16));
    float rpre = ((a0 + a1) + (a2 + a3)) + xr_t;
    float r = 1.f / (1.f + __expf(-rpre));
    rhsh[tid] = r * hj;
    __syncthreads();
    float c0 = 0, c1 = 0, c2 = 0, c3 = 0;
    const float4* rh4 = (const float4*)rhsh;
#pragma unroll
    for (int qi = 0; qi < 64; ++qi) {
      float4 hv = rh4[qi];
      unsigned p0 = wh[2 * qi], p1 = wh[2 * qi + 1];
      c0 = fmaf(blo(p0), hv.x, c0);
      c1 = fmaf(bhi(p0), hv.y, c1);
      c2 = fmaf(blo(p1), hv.z, c2);
      c3 = fmaf(bhi(p1), hv.w, c3);
    }
    float hpre = ((c0 + c1) + (c2 + c3)) + xh_t;
    float xc = fminf(fmaxf(hpre, -15.f), 15.f);
    float exv = __expf(2.f * xc);
    float hc = (exv - 1.f) / (exv + 1.f);
    float hn = hj + gt * (hc - hj);
    if (t < len) hj = hn;
    float e = (t < len) ? hj : 0.f;
    ep[((size_t)b * 512 + t) * 256 + tid] = f2b(e);
    hsh[tid] = hj;
    __syncthreads();
  }
}

// ---------------- final dense: out_s/out_e (fp32 output) ----------------
__global__ void k_out(const unsigned short* __restrict__ ep,
                      const void* __restrict__ Ws,
                      const void* __restrict__ We,
                      const float* __restrict__ qs,
                      const float* __restrict__ qe,
                      const int* __restrict__ mode,
                      float* __restrict__ out) {
  int md = *mode;
  int tid = threadIdx.x;
  int wave = tid >> 6, lane = tid & 63;
  int row = blockIdx.x * 4 + wave;  // (b,t) flat, 0..32767
  const unsigned short* er = ep + (size_t)row * 256 + lane * 4;
  float f0 = b2f(er[0]), f1 = b2f(er[1]), f2 = b2f(er[2]), f3 = b2f(er[3]);
  int n = 256 + lane * 4;
  float s = f0 * ldf(Ws, n, md) + f1 * ldf(Ws, n + 1, md) + f2 * ldf(Ws, n + 2, md) + f3 * ldf(Ws, n + 3, md);
  float e = f0 * ldf(We, n, md) + f1 * ldf(We, n + 1, md) + f2 * ldf(We, n + 2, md) + f3 * ldf(We, n + 3, md);
  for (int o = 32; o > 0; o >>= 1) { s += __shfl_down(s, o); e += __shfl_down(e, o); }
  if (lane == 0) {
    int b = row >> 9;
    out[row] = tanhf(qs[b] + s);
    out[32768 + row] = tanhf(qe[b] + e);
  }
}

extern "C" void kernel_launch(void* const* d_in, const int* in_sizes, int n_in,
                              void* d_out, int out_size, void* d_ws, size_t ws_size,
                              hipStream_t stream) {
  const void* q    = d_in[0];
  const void* fact = d_in[1];
  const int* ilen  = (const int*)d_in[2];
  const void* W1   = d_in[3];
  const void* b1   = d_in[4];
  const void* W2   = d_in[5];
  const void* b2v  = d_in[6];
  const void* Wr   = d_in[7];
  const void* Ur   = d_in[8];
  const void* br   = d_in[9];
  const void* Wh   = d_in[10];
  const void* Uh   = d_in[11];
  const void* bh   = d_in[12];
  const void* Ws   = d_in[13];
  const void* bs   = d_in[14];
  const void* We   = d_in[15];
  const void* be   = d_in[16];

  char* w = (char*)d_ws;
  float*    WK2 = (float*)(w);
  unsigned* Urp = (unsigned*)(w + 1310720);
  unsigned* Uhp = (unsigned*)(w + 1441792);
  float*    qw1 = (float*)(w + 1572864);
  float*    qs  = (float*)(w + 1638400);
  float*    qe  = (float*)(w + 1638656);
  float*    att = (float*)(w + 1638912);
  float*    g   = (float*)(w + 1769984);
  unsigned* xrh = (unsigned*)(w + 1901056);
  unsigned short* ep = (unsigned short*)(w + 35455488);
  int*      mode = (int*)(w + 52232704);
  float* out = (float*)d_out;

  k_detect<<<dim3(1), dim3(256), 0, stream>>>(fact, mode);
  k_prep_w<<<dim3(256), dim3(256), 0, stream>>>(W1, Wr, Wh, Ur, Uh, mode, WK2, Urp, Uhp);
  k_prep_q<<<dim3(64), dim3(256), 0, stream>>>(q, W1, b1, Ws, bs, We, be, mode, qw1, qs, qe);
  k_main<<<dim3(2048), dim3(256), 0, stream>>>(fact, q, WK2, qw1, W2, b2v, br, bh, mode, att, xrh);
  k_softmax<<<dim3(64), dim3(512), 0, stream>>>(att, g);
  k_scan<<<dim3(64), dim3(256), 0, stream>>>(Urp, Uhp, xrh, g, ilen, ep);
  k_out<<<dim3(8192), dim3(256), 0, stream>>>(ep, Ws, We, qs, qe, mode, out);
}

// Round 4
// 2876.744 us; speedup vs baseline: 1.6948x; 1.6948x over previous
//
#include <hip/hip_runtime.h>
#include <cstddef>

// B=64, T=512, H=256. Float inputs fp32 (runtime-detected, bf16 fallback).
// Output fp32: [out_s (B*T), out_e (B*T)].
// ws layout (bytes):
//   0        WK2   5*65536 f32  (W1f, W1fq+W1fm, W1afq+W1afm, Wr, Wh)
//   1310720  Urp   128*256 u32  (bf16 pairs along i)
//   1441792  Uhp   128*256 u32
//   1572864  qw1   64*256 f32   (b1 + q@(W1m+W1q))
//   1638400  qs    64 f32       (bs + q@Ws[0:256])
//   1638656  qe    64 f32
//   1638912  att   64*512 f32
//   1769984  g     64*512 f32
//   1901056  xrh   64*512*256 u32  (bf16(xr+br) | bf16(xh+bh)<<16)
//   35455488 ep    64*512*256 bf16 (e_outputs)
//   52232704 mode  int (0 = inputs are bf16, 1 = inputs are fp32)

static __device__ __forceinline__ float b2f(unsigned short u) {
  return __uint_as_float(((unsigned)u) << 16);
}
static __device__ __forceinline__ float blo(unsigned w) { return __uint_as_float(w << 16); }
static __device__ __forceinline__ float bhi(unsigned w) { return __uint_as_float(w & 0xffff0000u); }
static __device__ __forceinline__ unsigned short f2b(float f) {
  unsigned u = __float_as_uint(f);
  u += 0x7fffu + ((u >> 16) & 1u);  // RNE
  return (unsigned short)(u >> 16);
}
// adaptive input loads (md: 0=bf16 data, 1=fp32 data)
static __device__ __forceinline__ float ldf(const void* b, size_t i, int md) {
  return md ? ((const float*)b)[i] : b2f(((const unsigned short*)b)[i]);
}
static __device__ __forceinline__ unsigned short ldb(const void* b, size_t i, int md) {
  return md ? f2b(((const float*)b)[i]) : ((const unsigned short*)b)[i];
}

// ---------------- dtype detection ----------------
__global__ void k_detect(const void* __restrict__ fact, int* __restrict__ mode) {
  int tid = threadIdx.x;  // 256
  const unsigned short* u = (const unsigned short*)fact;
  float v = fabsf(b2f(u[2 * tid]));  // if fp32 data: low mantissa bits -> huge/NaN
  if (!(v == v)) v = 1e30f;
  for (int o = 32; o > 0; o >>= 1) v = fmaxf(v, __shfl_xor(v, o));
  __shared__ float red[4];
  int wave = tid >> 6, lane = tid & 63;
  if (lane == 0) red[wave] = v;
  __syncthreads();
  if (tid == 0) {
    float m = fmaxf(fmaxf(red[0], red[1]), fmaxf(red[2], red[3]));
    mode[0] = (m > 1e4f) ? 1 : 0;
  }
}

// ---------------- prep: combined weights + packed Ur/Uh ----------------
__global__ void k_prep_w(const void* __restrict__ W1,
                         const void* __restrict__ Wr,
                         const void* __restrict__ Wh,
                         const void* __restrict__ Ur,
                         const void* __restrict__ Uh,
                         const int* __restrict__ mode,
                         float* __restrict__ WK2,
                         unsigned* __restrict__ Urp,
                         unsigned* __restrict__ Uhp) {
  int md = *mode;
  int idx = blockIdx.x * 256 + threadIdx.x;  // 0..65535
  int i = idx >> 8, j = idx & 255;
  WK2[0 * 65536 + idx] = ldf(W1, idx, md);  // rows [0,256): f
  WK2[1 * 65536 + idx] = ldf(W1, (size_t)(768 + i) * 256 + j, md) + ldf(W1, (size_t)(1024 + i) * 256 + j, md);   // f*q
  WK2[2 * 65536 + idx] = ldf(W1, (size_t)(1280 + i) * 256 + j, md) + ldf(W1, (size_t)(1536 + i) * 256 + j, md);  // |f-q|
  WK2[3 * 65536 + idx] = ldf(Wr, idx, md);
  WK2[4 * 65536 + idx] = ldf(Wh, idx, md);
  if (i < 128) {
    Urp[idx] = (unsigned)ldb(Ur, (size_t)(2 * i) * 256 + j, md) |
               ((unsigned)ldb(Ur, (size_t)(2 * i + 1) * 256 + j, md) << 16);
    Uhp[idx] = (unsigned)ldb(Uh, (size_t)(2 * i) * 256 + j, md) |
               ((unsigned)ldb(Uh, (size_t)(2 * i + 1) * 256 + j, md) << 16);
  }
}

// ---------------- prep: q-dependent vectors ----------------
__global__ void k_prep_q(const void* __restrict__ q,
                         const void* __restrict__ W1,
                         const void* __restrict__ b1,
                         const void* __restrict__ Ws,
                         const void* __restrict__ bs,
                         const void* __restrict__ We,
                         const void* __restrict__ be,
                         const int* __restrict__ mode,
                         float* __restrict__ qw1,
                         float* __restrict__ qs,
                         float* __restrict__ qe) {
  __shared__ float qsh[256];
  __shared__ float reds[4], rede[4];
  int md = *mode;
  int b = blockIdx.x, tid = threadIdx.x;
  float qv = ldf(q, (size_t)b * 256 + tid, md);
  qsh[tid] = qv;
  __syncthreads();
  float acc = ldf(b1, tid, md);
  for (int i = 0; i < 256; ++i) {
    float w = ldf(W1, (size_t)(256 + i) * 256 + tid, md) + ldf(W1, (size_t)(512 + i) * 256 + tid, md);
    acc = fmaf(qsh[i], w, acc);
  }
  qw1[b * 256 + tid] = acc;
  float ps = qv * ldf(Ws, tid, md);
  float pe = qv * ldf(We, tid, md);
  for (int o = 32; o > 0; o >>= 1) { ps += __shfl_down(ps, o); pe += __shfl_down(pe, o); }
  int wave = tid >> 6, lane = tid & 63;
  if (lane == 0) { reds[wave] = ps; rede[wave] = pe; }
  __syncthreads();
  if (tid == 0) {
    qs[b] = ldf(bs, 0, md) + reds[0] + reds[1] + reds[2] + reds[3];
    qe[b] = ldf(be, 0, md) + rede[0] + rede[1] + rede[2] + rede[3];
  }
}

// ---------------- main GEMM: att pre-softmax + xr/xh ----------------
__launch_bounds__(256, 2)
__global__ void k_main(const void* __restrict__ fact,
                       const void* __restrict__ q,
                       const float* __restrict__ WK2,
                       const float* __restrict__ qw1,
                       const void* __restrict__ W2,
                       const void* __restrict__ b2v,
                       const void* __restrict__ br,
                       const void* __restrict__ bh,
                       const int* __restrict__ mode,
                       float* __restrict__ att,
                       unsigned* __restrict__ xrh) {
  __shared__ __align__(16) float sfT[256 * 20];  // [feature i][row r], stride 20
  __shared__ __align__(16) float sqT[256 * 20];
  __shared__ __align__(16) float saT[256 * 20];
  __shared__ float wsc[4 * 16];
  int md = *mode;
  int blk = blockIdx.x;
  int b = blk >> 5, t0 = (blk & 31) * 16;
  int tid = threadIdx.x;
  float qv = ldf(q, (size_t)b * 256 + tid, md);
  for (int r = 0; r < 16; ++r) {
    float f = ldf(fact, ((size_t)(b * 512 + t0 + r)) * 256 + tid, md);
    sfT[tid * 20 + r] = f;
    sqT[tid * 20 + r] = f * qv;
    saT[tid * 20 + r] = fabsf(f - qv);
  }
  __syncthreads();
  int jq = tid >> 2, rq = tid & 3;
  float u[4][4] = {{0}}, ar[4][4] = {{0}}, ah[4][4] = {{0}};
  const float* w0 = WK2 + jq * 4;
  const float* w1 = w0 + 65536;
  const float* w2 = w0 + 2 * 65536;
  const float* w3 = w0 + 3 * 65536;
  const float* w4 = w0 + 4 * 65536;
  for (int i = 0; i < 256; ++i) {
    float4 wf = *(const float4*)(w0 + i * 256);
    float4 wq = *(const float4*)(w1 + i * 256);
    float4 wa = *(const float4*)(w2 + i * 256);
    float4 wr4 = *(const float4*)(w3 + i * 256);
    float4 wh4 = *(const float4*)(w4 + i * 256);
    float4 s1 = *(const float4*)(sfT + i * 20 + rq * 4);
    float4 s2 = *(const float4*)(sqT + i * 20 + rq * 4);
    float4 s3 = *(const float4*)(saT + i * 20 + rq * 4);
    float s1a[4] = {s1.x, s1.y, s1.z, s1.w};
    float s2a[4] = {s2.x, s2.y, s2.z, s2.w};
    float s3a[4] = {s3.x, s3.y, s3.z, s3.w};
    float wfa[4] = {wf.x, wf.y, wf.z, wf.w};
    float wqa[4] = {wq.x, wq.y, wq.z, wq.w};
    float waa[4] = {wa.x, wa.y, wa.z, wa.w};
    float wra[4] = {wr4.x, wr4.y, wr4.z, wr4.w};
    float wha[4] = {wh4.x, wh4.y, wh4.z, wh4.w};
#pragma unroll
    for (int rr = 0; rr < 4; ++rr) {
#pragma unroll
      for (int jj = 0; jj < 4; ++jj) {
        u[rr][jj] = fmaf(s1a[rr], wfa[jj], u[rr][jj]);
        u[rr][jj] = fmaf(s2a[rr], wqa[jj], u[rr][jj]);
        u[rr][jj] = fmaf(s3a[rr], waa[jj], u[rr][jj]);
        ar[rr][jj] = fmaf(s1a[rr], wra[jj], ar[rr][jj]);
        ah[rr][jj] = fmaf(s1a[rr], wha[jj], ah[rr][jj]);
      }
    }
  }
  float qwv[4], w2v[4], brv[4], bhv[4];
#pragma unroll
  for (int jj = 0; jj < 4; ++jj) {
    int j = jq * 4 + jj;
    qwv[jj] = qw1[b * 256 + j];
    w2v[jj] = ldf(W2, j, md);
    brv[jj] = ldf(br, j, md);
    bhv[jj] = ldf(bh, j, md);
  }
  float patt[4];
#pragma unroll
  for (int rr = 0; rr < 4; ++rr) {
    float p = 0.f;
#pragma unroll
    for (int jj = 0; jj < 4; ++jj) {
      float hid = tanhf(u[rr][jj] + qwv[jj]);
      p = fmaf(hid, w2v[jj], p);
    }
    p += __shfl_down(p, 4);
    p += __shfl_down(p, 8);
    p += __shfl_down(p, 16);
    p += __shfl_down(p, 32);
    patt[rr] = p;
  }
  int wave = tid >> 6, lane = tid & 63;
  if (lane < 4) {
#pragma unroll
    for (int rr = 0; rr < 4; ++rr) wsc[wave * 16 + lane * 4 + rr] = patt[rr];
  }
  __syncthreads();
  if (tid < 16) {
    float s = wsc[tid] + wsc[16 + tid] + wsc[32 + tid] + wsc[48 + tid];
    att[b * 512 + t0 + tid] = s + ldf(b2v, 0, md);
  }
#pragma unroll
  for (int rr = 0; rr < 4; ++rr) {
    int t = t0 + rq * 4 + rr;
    unsigned vv[4];
#pragma unroll
    for (int jj = 0; jj < 4; ++jj) {
      unsigned lo = f2b(ar[rr][jj] + brv[jj]);
      unsigned hi = f2b(ah[rr][jj] + bhv[jj]);
      vv[jj] = lo | (hi << 16);
    }
    uint4 v;
    v.x = vv[0]; v.y = vv[1]; v.z = vv[2]; v.w = vv[3];
    *(uint4*)(xrh + ((size_t)(b * 512 + t)) * 256 + jq * 4) = v;
  }
}

// ---------------- softmax over T per batch ----------------
__global__ void k_softmax(const float* __restrict__ att, float* __restrict__ g) {
  __shared__ float red[8];
  int b = blockIdx.x, tid = threadIdx.x;  // 512 threads
  float v = att[b * 512 + tid];
  float m = v;
  for (int o = 32; o > 0; o >>= 1) m = fmaxf(m, __shfl_xor(m, o));
  int wave = tid >> 6, lane = tid & 63;
  if (lane == 0) red[wave] = m;
  __syncthreads();
  m = red[0];
#pragma unroll
  for (int w = 1; w < 8; ++w) m = fmaxf(m, red[w]);
  float e = __expf(v - m);
  float s = e;
  for (int o = 32; o > 0; o >>= 1) s += __shfl_xor(s, o);
  __syncthreads();
  if (lane == 0) red[wave] = s;
  __syncthreads();
  s = red[0] + red[1] + red[2] + red[3] + red[4] + red[5] + red[6] + red[7];
  g[b * 512 + tid] = e / s;
}

// ---------------- sequential GRU scan: one block per batch ----------------
// 1024 threads = 16 waves (4/SIMD) for latency hiding. thread=(j=tid&255,
// qd=tid>>8): j = output column, qd = K-quarter. 32 packed-bf16 u32 weights
// per matrix per thread (64 VGPRs total) leaves room for LDS-read batching.
__launch_bounds__(1024, 4)
__global__ void k_scan(const unsigned* __restrict__ Urp,
                       const unsigned* __restrict__ Uhp,
                       const unsigned* __restrict__ xrh,
                       const float* __restrict__ g,
                       const int* __restrict__ input_len,
                       unsigned short* __restrict__ ep) {
  __shared__ __align__(16) float hsh[256];
  __shared__ __align__(16) float rhsh[256];
  __shared__ float psum[1024];
  __shared__ float gsh[512];
  int b = blockIdx.x, tid = threadIdx.x;
  int j = tid & 255, qd = tid >> 8;
  unsigned wr[32], wh[32];
#pragma unroll
  for (int k = 0; k < 32; ++k) wr[k] = Urp[(qd * 32 + k) * 256 + j];
#pragma unroll
  for (int k = 0; k < 32; ++k) wh[k] = Uhp[(qd * 32 + k) * 256 + j];
  if (tid < 512) gsh[tid] = g[b * 512 + tid];
  if (tid < 256) hsh[tid] = 0.f;
  int len = input_len[b];
  float hj = 0.f;
  const unsigned* xp = xrh + (size_t)b * 512 * 256 + j;
  unsigned nxt = (qd == 0) ? xp[0] : 0u;
  __syncthreads();
  const float4* h4 = (const float4*)hsh;
  const float4* rh4 = (const float4*)rhsh;
  for (int t = 0; t < 512; ++t) {
    // phase 1: r-matvec partial over this thread's 64-element K-slice
    float a0 = 0.f, a1 = 0.f;
#pragma unroll
    for (int k4 = 0; k4 < 16; ++k4) {
      float4 hv = h4[qd * 16 + k4];  // wave-broadcast read (conflict-free)
      unsigned p0 = wr[2 * k4], p1 = wr[2 * k4 + 1];
      a0 = fmaf(blo(p0), hv.x, a0);
      a1 = fmaf(bhi(p0), hv.y, a1);
      a0 = fmaf(blo(p1), hv.z, a0);
      a1 = fmaf(bhi(p1), hv.w, a1);
    }
    psum[tid] = a0 + a1;
    __syncthreads();
    unsigned cur = nxt;
    // phase 2: reduce + sigmoid + r*h (waves 0-3 only; wave-uniform branch)
    if (qd == 0) {
      float rpre = psum[j] + psum[256 + j] + psum[512 + j] + psum[768 + j] + blo(cur);
      float r = 1.f / (1.f + __expf(-rpre));
      rhsh[j] = r * hj;
      nxt = xp[(size_t)((t + 1) & 511) * 256];  // prefetch next step
    }
    __syncthreads();
    // phase 3: hc-matvec partial
    float c0 = 0.f, c1 = 0.f;
#pragma unroll
    for (int k4 = 0; k4 < 16; ++k4) {
      float4 hv = rh4[qd * 16 + k4];
      unsigned p0 = wh[2 * k4], p1 = wh[2 * k4 + 1];
      c0 = fmaf(blo(p0), hv.x, c0);
      c1 = fmaf(bhi(p0), hv.y, c1);
      c0 = fmaf(blo(p1), hv.z, c0);
      c1 = fmaf(bhi(p1), hv.w, c1);
    }
    psum[tid] = c0 + c1;
    __syncthreads();
    // phase 4: reduce + tanh + gate + state update
    if (qd == 0) {
      float hpre = psum[j] + psum[256 + j] + psum[512 + j] + psum[768 + j] + bhi(cur);
      float xc = fminf(fmaxf(hpre, -15.f), 15.f);
      float exv = __expf(2.f * xc);
      float hc = (exv - 1.f) / (exv + 1.f);
      float gt = gsh[t];
      float hn = hj + gt * (hc - hj);
      if (t < len) hj = hn;
      hsh[j] = hj;
      ep[((size_t)b * 512 + t) * 256 + j] = f2b((t < len) ? hj : 0.f);
    }
    __syncthreads();
  }
}

// ---------------- final dense: out_s/out_e (fp32 output) ----------------
__global__ void k_out(const unsigned short* __restrict__ ep,
                      const void* __restrict__ Ws,
                      const void* __restrict__ We,
                      const float* __restrict__ qs,
                      const float* __restrict__ qe,
                      const int* __restrict__ mode,
                      float* __restrict__ out) {
  int md = *mode;
  int tid = threadIdx.x;
  int wave = tid >> 6, lane = tid & 63;
  int row = blockIdx.x * 4 + wave;  // (b,t) flat, 0..32767
  const unsigned short* er = ep + (size_t)row * 256 + lane * 4;
  float f0 = b2f(er[0]), f1 = b2f(er[1]), f2 = b2f(er[2]), f3 = b2f(er[3]);
  int n = 256 + lane * 4;
  float s = f0 * ldf(Ws, n, md) + f1 * ldf(Ws, n + 1, md) + f2 * ldf(Ws, n + 2, md) + f3 * ldf(Ws, n + 3, md);
  float e = f0 * ldf(We, n, md) + f1 * ldf(We, n + 1, md) + f2 * ldf(We, n + 2, md) + f3 * ldf(We, n + 3, md);
  for (int o = 32; o > 0; o >>= 1) { s += __shfl_down(s, o); e += __shfl_down(e, o); }
  if (lane == 0) {
    int b = row >> 9;
    out[row] = tanhf(qs[b] + s);
    out[32768 + row] = tanhf(qe[b] + e);
  }
}

extern "C" void kernel_launch(void* const* d_in, const int* in_sizes, int n_in,
                              void* d_out, int out_size, void* d_ws, size_t ws_size,
                              hipStream_t stream) {
  const void* q    = d_in[0];
  const void* fact = d_in[1];
  const int* ilen  = (const int*)d_in[2];
  const void* W1   = d_in[3];
  const void* b1   = d_in[4];
  const void* W2   = d_in[5];
  const void* b2v  = d_in[6];
  const void* Wr   = d_in[7];
  const void* Ur   = d_in[8];
  const void* br   = d_in[9];
  const void* Wh   = d_in[10];
  const void* Uh   = d_in[11];
  const void* bh   = d_in[12];
  const void* Ws   = d_in[13];
  const void* bs   = d_in[14];
  const void* We   = d_in[15];
  const void* be   = d_in[16];

  char* w = (char*)d_ws;
  float*    WK2 = (float*)(w);
  unsigned* Urp = (unsigned*)(w + 1310720);
  unsigned* Uhp = (unsigned*)(w + 1441792);
  float*    qw1 = (float*)(w + 1572864);
  float*    qs  = (float*)(w + 1638400);
  float*    qe  = (float*)(w + 1638656);
  float*    att = (float*)(w + 1638912);
  float*    g   = (float*)(w + 1769984);
  unsigned* xrh = (unsigned*)(w + 1901056);
  unsigned short* ep = (unsigned short*)(w + 35455488);
  int*      mode = (int*)(w + 52232704);
  float* out = (float*)d_out;

  k_detect<<<dim3(1), dim3(256), 0, stream>>>(fact, mode);
  k_prep_w<<<dim3(256), dim3(256), 0, stream>>>(W1, Wr, Wh, Ur, Uh, mode, WK2, Urp, Uhp);
  k_prep_q<<<dim3(64), dim3(256), 0, stream>>>(q, W1, b1, Ws, bs, We, be, mode, qw1, qs, qe);
  k_main<<<dim3(2048), dim3(256), 0, stream>>>(fact, q, WK2, qw1, W2, b2v, br, bh, mode, att, xrh);
  k_softmax<<<dim3(64), dim3(512), 0, stream>>>(att, g);
  k_scan<<<dim3(64), dim3(1024), 0, stream>>>(Urp, Uhp, xrh, g, ilen, ep);
  k_out<<<dim3(8192), dim3(256), 0, stream>>>(ep, Ws, We, qs, qe, mode, out);
}

// Round 5
// 2437.117 us; speedup vs baseline: 2.0005x; 1.1804x over previous
//
#include <hip/hip_runtime.h>
#include <cstddef>

// B=64, T=512, H=256. Float inputs fp32 (runtime-detected, bf16 fallback).
// Output fp32: [out_s (B*T), out_e (B*T)].
// ws layout (bytes):
//   0        WK2   5*65536 f32  (W1f, W1fq+W1fm, W1afq+W1afm, Wr, Wh)
//   1310720  Urp   128*256 u32  (bf16 pairs along i)
//   1441792  Uhp   128*256 u32
//   1572864  qw1   64*256 f32   (b1 + q@(W1m+W1q))
//   1638400  qs    64 f32       (bs + q@Ws[0:256])
//   1638656  qe    64 f32
//   1638912  att   64*512 f32
//   1769984  g     64*512 f32
//   1901056  xrh   64*512*256 u32  (bf16(xr+br) | bf16(xh+bh)<<16)
//   35455488 ep    64*512*256 bf16 (e_outputs)
//   52232704 mode  int (0 = inputs are bf16, 1 = inputs are fp32)

static __device__ __forceinline__ float b2f(unsigned short u) {
  return __uint_as_float(((unsigned)u) << 16);
}
static __device__ __forceinline__ float blo(unsigned w) { return __uint_as_float(w << 16); }
static __device__ __forceinline__ float bhi(unsigned w) { return __uint_as_float(w & 0xffff0000u); }
static __device__ __forceinline__ unsigned short f2b(float f) {
  unsigned u = __float_as_uint(f);
  u += 0x7fffu + ((u >> 16) & 1u);  // RNE
  return (unsigned short)(u >> 16);
}
// adaptive input loads (md: 0=bf16 data, 1=fp32 data)
static __device__ __forceinline__ float ldf(const void* b, size_t i, int md) {
  return md ? ((const float*)b)[i] : b2f(((const unsigned short*)b)[i]);
}
static __device__ __forceinline__ unsigned short ldb(const void* b, size_t i, int md) {
  return md ? f2b(((const float*)b)[i]) : ((const unsigned short*)b)[i];
}

// ---------------- dtype detection ----------------
__global__ void k_detect(const void* __restrict__ fact, int* __restrict__ mode) {
  int tid = threadIdx.x;  // 256
  const unsigned short* u = (const unsigned short*)fact;
  float v = fabsf(b2f(u[2 * tid]));  // if fp32 data: low mantissa bits -> huge/NaN
  if (!(v == v)) v = 1e30f;
  for (int o = 32; o > 0; o >>= 1) v = fmaxf(v, __shfl_xor(v, o));
  __shared__ float red[4];
  int wave = tid >> 6, lane = tid & 63;
  if (lane == 0) red[wave] = v;
  __syncthreads();
  if (tid == 0) {
    float m = fmaxf(fmaxf(red[0], red[1]), fmaxf(red[2], red[3]));
    mode[0] = (m > 1e4f) ? 1 : 0;
  }
}

// ---------------- prep: combined weights + packed Ur/Uh ----------------
__global__ void k_prep_w(const void* __restrict__ W1,
                         const void* __restrict__ Wr,
                         const void* __restrict__ Wh,
                         const void* __restrict__ Ur,
                         const void* __restrict__ Uh,
                         const int* __restrict__ mode,
                         float* __restrict__ WK2,
                         unsigned* __restrict__ Urp,
                         unsigned* __restrict__ Uhp) {
  int md = *mode;
  int idx = blockIdx.x * 256 + threadIdx.x;  // 0..65535
  int i = idx >> 8, j = idx & 255;
  WK2[0 * 65536 + idx] = ldf(W1, idx, md);  // rows [0,256): f
  WK2[1 * 65536 + idx] = ldf(W1, (size_t)(768 + i) * 256 + j, md) + ldf(W1, (size_t)(1024 + i) * 256 + j, md);   // f*q
  WK2[2 * 65536 + idx] = ldf(W1, (size_t)(1280 + i) * 256 + j, md) + ldf(W1, (size_t)(1536 + i) * 256 + j, md);  // |f-q|
  WK2[3 * 65536 + idx] = ldf(Wr, idx, md);
  WK2[4 * 65536 + idx] = ldf(Wh, idx, md);
  if (i < 128) {
    Urp[idx] = (unsigned)ldb(Ur, (size_t)(2 * i) * 256 + j, md) |
               ((unsigned)ldb(Ur, (size_t)(2 * i + 1) * 256 + j, md) << 16);
    Uhp[idx] = (unsigned)ldb(Uh, (size_t)(2 * i) * 256 + j, md) |
               ((unsigned)ldb(Uh, (size_t)(2 * i + 1) * 256 + j, md) << 16);
  }
}

// ---------------- prep: q-dependent vectors ----------------
__global__ void k_prep_q(const void* __restrict__ q,
                         const void* __restrict__ W1,
                         const void* __restrict__ b1,
                         const void* __restrict__ Ws,
                         const void* __restrict__ bs,
                         const void* __restrict__ We,
                         const void* __restrict__ be,
                         const int* __restrict__ mode,
                         float* __restrict__ qw1,
                         float* __restrict__ qs,
                         float* __restrict__ qe) {
  __shared__ float qsh[256];
  __shared__ float reds[4], rede[4];
  int md = *mode;
  int b = blockIdx.x, tid = threadIdx.x;
  float qv = ldf(q, (size_t)b * 256 + tid, md);
  qsh[tid] = qv;
  __syncthreads();
  float acc = ldf(b1, tid, md);
  for (int i = 0; i < 256; ++i) {
    float w = ldf(W1, (size_t)(256 + i) * 256 + tid, md) + ldf(W1, (size_t)(512 + i) * 256 + tid, md);
    acc = fmaf(qsh[i], w, acc);
  }
  qw1[b * 256 + tid] = acc;
  float ps = qv * ldf(Ws, tid, md);
  float pe = qv * ldf(We, tid, md);
  for (int o = 32; o > 0; o >>= 1) { ps += __shfl_down(ps, o); pe += __shfl_down(pe, o); }
  int wave = tid >> 6, lane = tid & 63;
  if (lane == 0) { reds[wave] = ps; rede[wave] = pe; }
  __syncthreads();
  if (tid == 0) {
    qs[b] = ldf(bs, 0, md) + reds[0] + reds[1] + reds[2] + reds[3];
    qe[b] = ldf(be, 0, md) + rede[0] + rede[1] + rede[2] + rede[3];
  }
}

// ---------------- main GEMM: att pre-softmax + xr/xh ----------------
__launch_bounds__(256, 2)
__global__ void k_main(const void* __restrict__ fact,
                       const void* __restrict__ q,
                       const float* __restrict__ WK2,
                       const float* __restrict__ qw1,
                       const void* __restrict__ W2,
                       const void* __restrict__ b2v,
                       const void* __restrict__ br,
                       const void* __restrict__ bh,
                       const int* __restrict__ mode,
                       float* __restrict__ att,
                       unsigned* __restrict__ xrh) {
  __shared__ __align__(16) float sfT[256 * 20];  // [feature i][row r], stride 20
  __shared__ __align__(16) float sqT[256 * 20];
  __shared__ __align__(16) float saT[256 * 20];
  __shared__ float wsc[4 * 16];
  int md = *mode;
  int blk = blockIdx.x;
  int b = blk >> 5, t0 = (blk & 31) * 16;
  int tid = threadIdx.x;
  float qv = ldf(q, (size_t)b * 256 + tid, md);
  for (int r = 0; r < 16; ++r) {
    float f = ldf(fact, ((size_t)(b * 512 + t0 + r)) * 256 + tid, md);
    sfT[tid * 20 + r] = f;
    sqT[tid * 20 + r] = f * qv;
    saT[tid * 20 + r] = fabsf(f - qv);
  }
  __syncthreads();
  int jq = tid >> 2, rq = tid & 3;
  float u[4][4] = {{0}}, ar[4][4] = {{0}}, ah[4][4] = {{0}};
  const float* w0 = WK2 + jq * 4;
  const float* w1 = w0 + 65536;
  const float* w2 = w0 + 2 * 65536;
  const float* w3 = w0 + 3 * 65536;
  const float* w4 = w0 + 4 * 65536;
  for (int i = 0; i < 256; ++i) {
    float4 wf = *(const float4*)(w0 + i * 256);
    float4 wq = *(const float4*)(w1 + i * 256);
    float4 wa = *(const float4*)(w2 + i * 256);
    float4 wr4 = *(const float4*)(w3 + i * 256);
    float4 wh4 = *(const float4*)(w4 + i * 256);
    float4 s1 = *(const float4*)(sfT + i * 20 + rq * 4);
    float4 s2 = *(const float4*)(sqT + i * 20 + rq * 4);
    float4 s3 = *(const float4*)(saT + i * 20 + rq * 4);
    float s1a[4] = {s1.x, s1.y, s1.z, s1.w};
    float s2a[4] = {s2.x, s2.y, s2.z, s2.w};
    float s3a[4] = {s3.x, s3.y, s3.z, s3.w};
    float wfa[4] = {wf.x, wf.y, wf.z, wf.w};
    float wqa[4] = {wq.x, wq.y, wq.z, wq.w};
    float waa[4] = {wa.x, wa.y, wa.z, wa.w};
    float wra[4] = {wr4.x, wr4.y, wr4.z, wr4.w};
    float wha[4] = {wh4.x, wh4.y, wh4.z, wh4.w};
#pragma unroll
    for (int rr = 0; rr < 4; ++rr) {
#pragma unroll
      for (int jj = 0; jj < 4; ++jj) {
        u[rr][jj] = fmaf(s1a[rr], wfa[jj], u[rr][jj]);
        u[rr][jj] = fmaf(s2a[rr], wqa[jj], u[rr][jj]);
        u[rr][jj] = fmaf(s3a[rr], waa[jj], u[rr][jj]);
        ar[rr][jj] = fmaf(s1a[rr], wra[jj], ar[rr][jj]);
        ah[rr][jj] = fmaf(s1a[rr], wha[jj], ah[rr][jj]);
      }
    }
  }
  float qwv[4], w2v[4], brv[4], bhv[4];
#pragma unroll
  for (int jj = 0; jj < 4; ++jj) {
    int j = jq * 4 + jj;
    qwv[jj] = qw1[b * 256 + j];
    w2v[jj] = ldf(W2, j, md);
    brv[jj] = ldf(br, j, md);
    bhv[jj] = ldf(bh, j, md);
  }
  float patt[4];
#pragma unroll
  for (int rr = 0; rr < 4; ++rr) {
    float p = 0.f;
#pragma unroll
    for (int jj = 0; jj < 4; ++jj) {
      float hid = tanhf(u[rr][jj] + qwv[jj]);
      p = fmaf(hid, w2v[jj], p);
    }
    p += __shfl_down(p, 4);
    p += __shfl_down(p, 8);
    p += __shfl_down(p, 16);
    p += __shfl_down(p, 32);
    patt[rr] = p;
  }
  int wave = tid >> 6, lane = tid & 63;
  if (lane < 4) {
#pragma unroll
    for (int rr = 0; rr < 4; ++rr) wsc[wave * 16 + lane * 4 + rr] = patt[rr];
  }
  __syncthreads();
  if (tid < 16) {
    float s = wsc[tid] + wsc[16 + tid] + wsc[32 + tid] + wsc[48 + tid];
    att[b * 512 + t0 + tid] = s + ldf(b2v, 0, md);
  }
#pragma unroll
  for (int rr = 0; rr < 4; ++rr) {
    int t = t0 + rq * 4 + rr;
    unsigned vv[4];
#pragma unroll
    for (int jj = 0; jj < 4; ++jj) {
      unsigned lo = f2b(ar[rr][jj] + brv[jj]);
      unsigned hi = f2b(ah[rr][jj] + bhv[jj]);
      vv[jj] = lo | (hi << 16);
    }
    uint4 v;
    v.x = vv[0]; v.y = vv[1]; v.z = vv[2]; v.w = vv[3];
    *(uint4*)(xrh + ((size_t)(b * 512 + t)) * 256 + jq * 4) = v;
  }
}

// ---------------- softmax over T per batch ----------------
__global__ void k_softmax(const float* __restrict__ att, float* __restrict__ g) {
  __shared__ float red[8];
  int b = blockIdx.x, tid = threadIdx.x;  // 512 threads
  float v = att[b * 512 + tid];
  float m = v;
  for (int o = 32; o > 0; o >>= 1) m = fmaxf(m, __shfl_xor(m, o));
  int wave = tid >> 6, lane = tid & 63;
  if (lane == 0) red[wave] = m;
  __syncthreads();
  m = red[0];
#pragma unroll
  for (int w = 1; w < 8; ++w) m = fmaxf(m, red[w]);
  float e = __expf(v - m);
  float s = e;
  for (int o = 32; o > 0; o >>= 1) s += __shfl_xor(s, o);
  __syncthreads();
  if (lane == 0) red[wave] = s;
  __syncthreads();
  s = red[0] + red[1] + red[2] + red[3] + red[4] + red[5] + red[6] + red[7];
  g[b * 512 + tid] = e / s;
}

// ---------------- sequential GRU scan: one block per batch ----------------
// 1024 threads = 16 waves. Wave w owns 16 columns j=w*16+c; lane=(c=lane&15,
// qd=lane>>4) holds the 64-element K-slice [qd*64, qd*64+64) of columns j.
// K-reduction via shfl_xor(16/32) -> only 2 barriers/step (rh and h exchange).
// x input staged in 32-step LDS chunks; e output buffered in LDS, flushed
// every 32 steps -> no per-step global ops (no vmcnt drain at barriers).
__launch_bounds__(1024, 4)
__global__ void k_scan(const unsigned* __restrict__ Urp,
                       const unsigned* __restrict__ Uhp,
                       const unsigned* __restrict__ xrh,
                       const float* __restrict__ g,
                       const int* __restrict__ input_len,
                       unsigned short* __restrict__ ep) {
  // padded h/rh: f(k) = k + (k>>6)*4 -> qd-slices start at banks 0/4/8/12
  __shared__ __align__(16) float hsh[272];
  __shared__ __align__(16) float rhsh[272];
  __shared__ float gsh[512];
  __shared__ __align__(16) unsigned xb[32 * 256];        // 32 KB
  __shared__ __align__(16) unsigned short epb[32 * 256]; // 16 KB
  int b = blockIdx.x, tid = threadIdx.x;
  int wave = tid >> 6, lane = tid & 63;
  int c = lane & 15, qd = lane >> 4;
  int j = wave * 16 + c;
  int jp = j + (j >> 6) * 4;  // padded index
  unsigned wr[32], wh[32];
#pragma unroll
  for (int p = 0; p < 32; ++p) wr[p] = Urp[(qd * 32 + p) * 256 + j];
#pragma unroll
  for (int p = 0; p < 32; ++p) wh[p] = Uhp[(qd * 32 + p) * 256 + j];
  if (tid < 512) gsh[tid] = g[b * 512 + tid];
  if (tid < 272) { hsh[tid] = 0.f; rhsh[tid] = 0.f; }
  int len = input_len[b];
  float hj = 0.f;  // this lane's copy of h[j] (identical across qd)
  const float4* h4 = (const float4*)hsh;
  const float4* rh4 = (const float4*)rhsh;
  const uint4* xsrc = (const uint4*)(xrh + (size_t)b * 131072);
  __syncthreads();
  for (int t = 0; t < 512; ++t) {
    if ((t & 31) == 0) {
      // stage next 32 steps of x into LDS (2048 uint4)
      uint4 v0 = xsrc[(t >> 5) * 2048 + tid];
      uint4 v1 = xsrc[(t >> 5) * 2048 + 1024 + tid];
      ((uint4*)xb)[tid] = v0;
      ((uint4*)xb)[tid + 1024] = v1;
      __syncthreads();
    }
    // phase A: r-matvec over K-slice, reduce across qd in-register
    float a0 = 0.f, a1 = 0.f;
#pragma unroll
    for (int p = 0; p < 16; ++p) {
      float4 hv = h4[qd * 17 + p];
      unsigned p0 = wr[2 * p], p1 = wr[2 * p + 1];
      a0 = fmaf(blo(p0), hv.x, a0);
      a1 = fmaf(bhi(p0), hv.y, a1);
      a0 = fmaf(blo(p1), hv.z, a0);
      a1 = fmaf(bhi(p1), hv.w, a1);
    }
    float dot = a0 + a1;
    dot += __shfl_xor(dot, 16);
    dot += __shfl_xor(dot, 32);
    unsigned cur = xb[(t & 31) * 256 + j];  // broadcast among qd copies
    float r = 1.f / (1.f + __expf(-(dot + blo(cur))));
    if (qd == 0) rhsh[jp] = r * hj;
    __syncthreads();
    // phase B: hc-matvec over K-slice
    float c0 = 0.f, c1 = 0.f;
#pragma unroll
    for (int p = 0; p < 16; ++p) {
      float4 rv = rh4[qd * 17 + p];
      unsigned p0 = wh[2 * p], p1 = wh[2 * p + 1];
      c0 = fmaf(blo(p0), rv.x, c0);
      c1 = fmaf(bhi(p0), rv.y, c1);
      c0 = fmaf(blo(p1), rv.z, c0);
      c1 = fmaf(bhi(p1), rv.w, c1);
    }
    float dc = c0 + c1;
    dc += __shfl_xor(dc, 16);
    dc += __shfl_xor(dc, 32);
    float hpre = dc + bhi(cur);
    float xc = fminf(fmaxf(hpre, -15.f), 15.f);
    float exv = __expf(2.f * xc);
    float hc = (exv - 1.f) / (exv + 1.f);
    float gt = gsh[t];
    float hn = hj + gt * (hc - hj);
    bool valid = t < len;
    hj = valid ? hn : hj;
    float e = valid ? hj : 0.f;
    if (qd == 0) {
      hsh[jp] = hj;
      epb[(t & 31) * 256 + j] = f2b(e);
    }
    __syncthreads();
    if ((t & 31) == 31) {
      // flush 32 steps of e (1024 uint4, coalesced); ds-reads drain at the
      // next chunk's barrier, stores drain there too (amortized 32x)
      uint4 ev = ((const uint4*)epb)[tid];
      ((uint4*)(ep + (size_t)b * 131072 + (size_t)(t - 31) * 256))[tid] = ev;
    }
  }
}

// ---------------- final dense: out_s/out_e (fp32 output) ----------------
__global__ void k_out(const unsigned short* __restrict__ ep,
                      const void* __restrict__ Ws,
                      const void* __restrict__ We,
                      const float* __restrict__ qs,
                      const float* __restrict__ qe,
                      const int* __restrict__ mode,
                      float* __restrict__ out) {
  int md = *mode;
  int tid = threadIdx.x;
  int wave = tid >> 6, lane = tid & 63;
  int row = blockIdx.x * 4 + wave;  // (b,t) flat, 0..32767
  const unsigned short* er = ep + (size_t)row * 256 + lane * 4;
  float f0 = b2f(er[0]), f1 = b2f(er[1]), f2 = b2f(er[2]), f3 = b2f(er[3]);
  int n = 256 + lane * 4;
  float s = f0 * ldf(Ws, n, md) + f1 * ldf(Ws, n + 1, md) + f2 * ldf(Ws, n + 2, md) + f3 * ldf(Ws, n + 3, md);
  float e = f0 * ldf(We, n, md) + f1 * ldf(We, n + 1, md) + f2 * ldf(We, n + 2, md) + f3 * ldf(We, n + 3, md);
  for (int o = 32; o > 0; o >>= 1) { s += __shfl_down(s, o); e += __shfl_down(e, o); }
  if (lane == 0) {
    int b = row >> 9;
    out[row] = tanhf(qs[b] + s);
    out[32768 + row] = tanhf(qe[b] + e);
  }
}

extern "C" void kernel_launch(void* const* d_in, const int* in_sizes, int n_in,
                              void* d_out, int out_size, void* d_ws, size_t ws_size,
                              hipStream_t stream) {
  const void* q    = d_in[0];
  const void* fact = d_in[1];
  const int* ilen  = (const int*)d_in[2];
  const void* W1   = d_in[3];
  const void* b1   = d_in[4];
  const void* W2   = d_in[5];
  const void* b2v  = d_in[6];
  const void* Wr   = d_in[7];
  const void* Ur   = d_in[8];
  const void* br   = d_in[9];
  const void* Wh   = d_in[10];
  const void* Uh   = d_in[11];
  const void* bh   = d_in[12];
  const void* Ws   = d_in[13];
  const void* bs   = d_in[14];
  const void* We   = d_in[15];
  const void* be   = d_in[16];

  char* w = (char*)d_ws;
  float*    WK2 = (float*)(w);
  unsigned* Urp = (unsigned*)(w + 1310720);
  unsigned* Uhp = (unsigned*)(w + 1441792);
  float*    qw1 = (float*)(w + 1572864);
  float*    qs  = (float*)(w + 1638400);
  float*    qe  = (float*)(w + 1638656);
  float*    att = (float*)(w + 1638912);
  float*    g   = (float*)(w + 1769984);
  unsigned* xrh = (unsigned*)(w + 1901056);
  unsigned short* ep = (unsigned short*)(w + 35455488);
  int*      mode = (int*)(w + 52232704);
  float* out = (float*)d_out;

  k_detect<<<dim3(1), dim3(256), 0, stream>>>(fact, mode);
  k_prep_w<<<dim3(256), dim3(256), 0, stream>>>(W1, Wr, Wh, Ur, Uh, mode, WK2, Urp, Uhp);
  k_prep_q<<<dim3(64), dim3(256), 0, stream>>>(q, W1, b1, Ws, bs, We, be, mode, qw1, qs, qe);
  k_main<<<dim3(2048), dim3(256), 0, stream>>>(fact, q, WK2, qw1, W2, b2v, br, bh, mode, att, xrh);
  k_softmax<<<dim3(64), dim3(512), 0, stream>>>(att, g);
  k_scan<<<dim3(64), dim3(1024), 0, stream>>>(Urp, Uhp, xrh, g, ilen, ep);
  k_out<<<dim3(8192), dim3(256), 0, stream>>>(ep, Ws, We, qs, qe, mode, out);
}